// Round 4
// baseline (62.976 us; speedup 1.0000x reference)
//
#include <hip/hip_runtime.h>

// MultiHeadDense: out[b] = x[b] @ W[idx[b]] + bias[idx[b]]
// B=4096, D=1024, F=1024, H=8. fp32 in/out; bf16 MFMA internally.
// Pipeline: k_prep (W transpose->bf16 + scan-based row binning, no atomics)
//           k_gather (permuted X copy fp32->bf16)
//           k_gemm (grouped 128x128 MFMA GEMM, 4-deep counted-vmcnt pipeline)

typedef __attribute__((ext_vector_type(8))) short bf16x8;
typedef __attribute__((ext_vector_type(4))) float f32x4;

#define WAITV(N) asm volatile("s_waitcnt vmcnt(" #N ")" ::: "memory")

static __device__ __forceinline__ unsigned short f2bf(float f) {
  union { float f; unsigned int u; } c; c.f = f;
  unsigned int u = c.u;
  return (unsigned short)((u + 0x7fffu + ((u >> 16) & 1u)) >> 16);
}

static __device__ __forceinline__ void gload16(const void* g, void* s) {
  __builtin_amdgcn_global_load_lds(
      (const __attribute__((address_space(1))) void*)g,
      (__attribute__((address_space(3))) void*)s, 16, 0, 0);
}

// Kernel 1 (fused): blocks 0..2047 transpose+convert W [H][D][F] fp32 ->
// Wt [H][F][D] bf16 in 64x64 tiles. Block 2048: deterministic counting-sort
// scan of idx -> rows[] (stable partition by head) + cnt[]. No atomics.
__global__ __launch_bounds__(256) void k_prep(
    const float* __restrict__ W, const int* __restrict__ idx,
    unsigned short* __restrict__ Wt, int* __restrict__ cnt,
    int* __restrict__ rows) {
  const int bid = blockIdx.x;
  const int t = threadIdx.x;

  if (bid >= 2048) {
    // ---- scan block: stable counting sort of 4096 indices into 8 bins ----
    __shared__ int sc[256][8];
    int myi[16];
#pragma unroll
    for (int i = 0; i < 4; ++i) {
      const int4 v = *(const int4*)(idx + t * 16 + i * 4);
      myi[i * 4 + 0] = v.x; myi[i * 4 + 1] = v.y;
      myi[i * 4 + 2] = v.z; myi[i * 4 + 3] = v.w;
    }
    int c[8];
#pragma unroll
    for (int h = 0; h < 8; ++h) c[h] = 0;
#pragma unroll
    for (int e = 0; e < 16; ++e)
#pragma unroll
      for (int h = 0; h < 8; ++h) c[h] += (myi[e] == h) ? 1 : 0;

    int val[8];
#pragma unroll
    for (int h = 0; h < 8; ++h) { val[h] = c[h]; sc[t][h] = c[h]; }
    __syncthreads();
    for (int off = 1; off < 256; off <<= 1) {
      int nb[8];
#pragma unroll
      for (int h = 0; h < 8; ++h) nb[h] = (t >= off) ? sc[t - off][h] : 0;
      __syncthreads();
#pragma unroll
      for (int h = 0; h < 8; ++h) { val[h] += nb[h]; sc[t][h] = val[h]; }
      __syncthreads();
    }
    int tot[8], base[8], excl[8];
#pragma unroll
    for (int h = 0; h < 8; ++h) tot[h] = sc[255][h];
    int a = 0;
#pragma unroll
    for (int h = 0; h < 8; ++h) { base[h] = a; a += tot[h]; }
#pragma unroll
    for (int h = 0; h < 8; ++h) excl[h] = val[h] - c[h];
#pragma unroll
    for (int h = 0; h < 8; ++h) {
      int pos = base[h] + excl[h];
#pragma unroll
      for (int e = 0; e < 16; ++e) {
        if (myi[e] == h) { rows[pos] = t * 16 + e; ++pos; }
      }
    }
    if (t < 8) cnt[t] = tot[t];
    return;
  }

  // ---- transpose block: 64x64 tile of head h ----
  __shared__ unsigned short tile[64][68];
  const int h = bid >> 8;
  const int rem = bid & 255;
  const int d0 = (rem >> 4) << 6;
  const int f0 = (rem & 15) << 6;
  const int c4 = (t & 15) * 4;
  const int r0 = t >> 4;
#pragma unroll
  for (int i = 0; i < 4; ++i) {
    const int r = r0 + i * 16;
    const float4 v = *(const float4*)(W + (size_t)(h * 1024 + d0 + r) * 1024 + f0 + c4);
    tile[r][c4 + 0] = f2bf(v.x);
    tile[r][c4 + 1] = f2bf(v.y);
    tile[r][c4 + 2] = f2bf(v.z);
    tile[r][c4 + 3] = f2bf(v.w);
  }
  __syncthreads();
#pragma unroll
  for (int i = 0; i < 4; ++i) {
    const int fr = r0 + i * 16;
    ushort4 o;
    o.x = tile[c4 + 0][fr];
    o.y = tile[c4 + 1][fr];
    o.z = tile[c4 + 2][fr];
    o.w = tile[c4 + 3][fr];
    *(ushort4*)(Wt + (size_t)(h * 1024 + f0 + fr) * 1024 + d0 + c4) = o;
  }
}

// Kernel 2: permuted gather-copy X row rows[slot] -> Ap[slot], fp32->bf16.
__global__ __launch_bounds__(256) void k_gather(
    const float* __restrict__ X, const int* __restrict__ rows,
    unsigned short* __restrict__ Ap) {
  const int slot = blockIdx.x;
  const int b = rows[slot];
  const int t = threadIdx.x;
  const float4 v = *(const float4*)(X + (size_t)b * 1024 + t * 4);
  ushort4 o;
  o.x = f2bf(v.x); o.y = f2bf(v.y); o.z = f2bf(v.z); o.w = f2bf(v.w);
  *(ushort4*)(Ap + (size_t)slot * 1024 + t * 4) = o;
}

// Kernel 3: grouped GEMM, 128x128 tile, BK=64, 4 waves (2x2, each 64x64,
// 4x4 fragment accs). 4-deep LDS ring (128 KB), raw s_barrier + counted
// s_waitcnt vmcnt(N) (never 0 in main loop) so prefetch stays in flight
// across barriers (T3/T4). XOR-swizzled LDS both-sides (rule 21):
// linear global_load_lds dest + pre-swizzled global source + XOR on ds_read.
// Ring safety: stage t+3 (issued AFTER compute of step t) writes buf
// (t+3)&3, whose last readers ran at step t-1 and completed before the
// barrier at step t (lgkm wait precedes MFMA precedes barrier; sched_barrier
// pins ordering). 1 block/CU by LDS; head = blk&7 for XCD L2 affinity.
__global__ __launch_bounds__(256) void k_gemm(
    const unsigned short* __restrict__ Ap, const unsigned short* __restrict__ Wt,
    const int* __restrict__ rows, const int* __restrict__ cnt,
    const float* __restrict__ bias, float* __restrict__ out) {
  __shared__ __align__(16) unsigned short As[4][128 * 64];
  __shared__ __align__(16) unsigned short Bs[4][128 * 64];

  const int blk = blockIdx.x;
  const int h = blk & 7;          // head -> XCD affinity
  const int nt = (blk >> 3) & 7;  // 8 n-tiles of 128
  const int mt = blk >> 6;        // up to 32 m-tiles of 128

  int cnt_h = 0, basep = 0;
#pragma unroll
  for (int i = 0; i < 8; ++i) {
    const int c = cnt[i];
    basep += (i < h) ? c : 0;
    if (i == h) cnt_h = c;
  }
  const int m0 = mt * 128;
  if (m0 >= cnt_h) return;
  const int n0 = nt * 128;

  const int t = threadIdx.x;
  const int lane = t & 63;
  const int wave = t >> 6;
  const int wr = wave >> 1, wc = wave & 1;

  const char* Ag = (const char*)(Ap + (size_t)(basep + m0) * 1024);
  const char* Bg = (const char*)(Wt + ((size_t)h * 1024 + n0) * 1024);

  // staging: round r covers rows r*32 + (t>>3); 8 x 16B chunks per row.
  const int srow = t >> 3;                              // 0..31
  const int scolS = (((t & 7) ^ (srow & 7)) << 4);      // pre-swizzled source col

  f32x4 acc[4][4];
#pragma unroll
  for (int m = 0; m < 4; ++m)
#pragma unroll
    for (int n = 0; n < 4; ++n)
      acc[m][n] = (f32x4){0.f, 0.f, 0.f, 0.f};

  auto stage = [&](int s, int k0) {  // 8 gload16 per thread
#pragma unroll
    for (int r = 0; r < 4; ++r)
      gload16(Ag + (size_t)(r * 32 + srow) * 2048 + k0 * 2 + scolS,
              (char*)(&As[s][0]) + r * 4096 + t * 16);
#pragma unroll
    for (int r = 0; r < 4; ++r)
      gload16(Bg + (size_t)(r * 32 + srow) * 2048 + k0 * 2 + scolS,
              (char*)(&Bs[s][0]) + r * 4096 + t * 16);
  };

  const int swz = (lane & 7) << 4;
  const int ra = (wr * 64 + (lane & 15)) * 128;  // byte base of A frag rows
  const int rb = (wc * 64 + (lane & 15)) * 128;
  const int kc = (lane >> 4) << 4;

  auto compute = [&](int s) {
    const char* ab = (const char*)(&As[s][0]);
    const char* bb = (const char*)(&Bs[s][0]);
#pragma unroll
    for (int ksub = 0; ksub < 2; ++ksub) {
      const int co = ((ksub * 64) + kc) ^ swz;
      bf16x8 af[4], bfr[4];
#pragma unroll
      for (int a = 0; a < 4; ++a)
        af[a] = *(const bf16x8*)(ab + ra + a * 2048 + co);
#pragma unroll
      for (int b = 0; b < 4; ++b)
        bfr[b] = *(const bf16x8*)(bb + rb + b * 2048 + co);
#pragma unroll
      for (int a = 0; a < 4; ++a)
#pragma unroll
        for (int b = 0; b < 4; ++b)
          acc[a][b] = __builtin_amdgcn_mfma_f32_16x16x32_bf16(af[a], bfr[b], acc[a][b], 0, 0, 0);
    }
  };

  // prologue: 3 stages in flight (24 loads/thread outstanding)
  stage(0, 0);
  stage(1, 64);
  stage(2, 128);

  for (int ts = 0; ts < 14; ++ts) {
    WAITV(16);                          // oldest stage landed; 2 stay in flight
    __builtin_amdgcn_s_barrier();
    __builtin_amdgcn_sched_barrier(0);
    compute(ts & 3);
    if (ts < 13) stage((ts + 3) & 3, (ts + 3) * 64);
  }
  WAITV(8);
  __builtin_amdgcn_s_barrier();
  __builtin_amdgcn_sched_barrier(0);
  compute(14 & 3);
  WAITV(0);
  __builtin_amdgcn_s_barrier();
  __builtin_amdgcn_sched_barrier(0);
  compute(15 & 3);

  // Epilogue: scatter through rows[] map, add bias (fp32).
  int rmap[4][4];
  bool vld[4][4];
#pragma unroll
  for (int m = 0; m < 4; ++m) {
#pragma unroll
    for (int j = 0; j < 4; ++j) {
      const int lr = wr * 64 + m * 16 + (lane >> 4) * 4 + j;
      const bool v = (m0 + lr) < cnt_h;
      vld[m][j] = v;
      rmap[m][j] = v ? rows[basep + m0 + lr] : 0;
    }
  }
#pragma unroll
  for (int n = 0; n < 4; ++n) {
    const int c = n0 + wc * 64 + n * 16 + (lane & 15);
    const float bv = bias[h * 1024 + c];
#pragma unroll
    for (int m = 0; m < 4; ++m) {
#pragma unroll
      for (int j = 0; j < 4; ++j) {
        if (vld[m][j])
          out[(size_t)rmap[m][j] * 1024 + c] = acc[m][n][j] + bv;
      }
    }
  }
}

extern "C" void kernel_launch(void* const* d_in, const int* in_sizes, int n_in,
                              void* d_out, int out_size, void* d_ws, size_t ws_size,
                              hipStream_t stream) {
  const float* X = (const float*)d_in[0];
  const int* idx = (const int*)d_in[1];
  const float* W = (const float*)d_in[2];
  const float* bias = (const float*)d_in[3];
  float* out = (float*)d_out;

  char* ws = (char*)d_ws;
  int* cnt = (int*)ws;                                   // 8 ints
  int* rows = (int*)(ws + 256);                          // 4096 ints
  unsigned short* Wt = (unsigned short*)(ws + 32768);    // 8*1024*1024 bf16 = 16 MB
  unsigned short* Ap = (unsigned short*)(ws + 32768 + 16777216);  // (4096+128)*1024 bf16

  k_prep<<<dim3(2049), 256, 0, stream>>>(W, idx, Wt, cnt, rows);
  k_gather<<<dim3(4096), 256, 0, stream>>>(X, rows, Ap);
  // 8 heads (xcd-affine) x 8 n-tiles x 32 m-tiles (early-return past cnt_h)
  k_gemm<<<dim3(8 * 8 * 32), 256, 0, stream>>>(Ap, Wt, rows, cnt, bias, out);
}

// Round 5
// 55.168 us; speedup vs baseline: 1.1415x; 1.1415x over previous
//
#include <hip/hip_runtime.h>

// MultiHeadDense: out[b] = x[b] @ W[idx[b]] + bias[idx[b]]
// B=4096, D=1024, F=1024, H=8. fp32 in/out; bf16 MFMA internally.
// Key idea this round: staging is the bottleneck (t = staged_bytes/rate(waves)).
// -> global_load_lds sources are LINEAR (max coalescing); the LDS bank-conflict
//    XOR swizzle is BAKED INTO the storage of Ap/Wt by k_prep/k_gather.
// -> head slot bases aligned to 8 so (slot&7)==(tile_row&7) for the bake.
// -> k_gemm: 128x128 tile, BK=64, dbuf (64KB LDS -> 2 blocks/CU, 8 waves/CU),
//    counted vmcnt(8), never 0 in main loop.

typedef __attribute__((ext_vector_type(8))) short bf16x8;
typedef __attribute__((ext_vector_type(4))) float f32x4;

#define WAITV(N) asm volatile("s_waitcnt vmcnt(" #N ")" ::: "memory")

static __device__ __forceinline__ unsigned short f2bf(float f) {
  union { float f; unsigned int u; } c; c.f = f;
  unsigned int u = c.u;
  return (unsigned short)((u + 0x7fffu + ((u >> 16) & 1u)) >> 16);
}

static __device__ __forceinline__ void gload16(const void* g, void* s) {
  __builtin_amdgcn_global_load_lds(
      (const __attribute__((address_space(1))) void*)g,
      (__attribute__((address_space(3))) void*)s, 16, 0, 0);
}

// Kernel 1 (fused): blocks 0..2047 transpose+convert W [H][D][F] fp32 ->
// Wt [H][F][D-swizzled] bf16 (chunk c of each 64-K group stored at c^(frow&7)).
// Block 2048: counting-sort scan of idx -> rows[] + cnt[] + base8[] (8-aligned
// head bases; gap slots zero-filled). No atomics anywhere.
__global__ __launch_bounds__(256) void k_prep(
    const float* __restrict__ W, const int* __restrict__ idx,
    unsigned short* __restrict__ Wt, int* __restrict__ cnt,
    int* __restrict__ base8, int* __restrict__ rows) {
  const int bid = blockIdx.x;
  const int t = threadIdx.x;

  if (bid >= 2048) {
    __shared__ int sc[256][8];
    int myi[16];
#pragma unroll
    for (int i = 0; i < 4; ++i) {
      const int4 v = *(const int4*)(idx + t * 16 + i * 4);
      myi[i * 4 + 0] = v.x; myi[i * 4 + 1] = v.y;
      myi[i * 4 + 2] = v.z; myi[i * 4 + 3] = v.w;
    }
    int c[8];
#pragma unroll
    for (int h = 0; h < 8; ++h) c[h] = 0;
#pragma unroll
    for (int e = 0; e < 16; ++e)
#pragma unroll
      for (int h = 0; h < 8; ++h) c[h] += (myi[e] == h) ? 1 : 0;

    int val[8];
#pragma unroll
    for (int h = 0; h < 8; ++h) { val[h] = c[h]; sc[t][h] = c[h]; }
    __syncthreads();
    for (int off = 1; off < 256; off <<= 1) {
      int nb[8];
#pragma unroll
      for (int h = 0; h < 8; ++h) nb[h] = (t >= off) ? sc[t - off][h] : 0;
      __syncthreads();
#pragma unroll
      for (int h = 0; h < 8; ++h) { val[h] += nb[h]; sc[t][h] = val[h]; }
      __syncthreads();
    }
    int tot[8], excl[8];
#pragma unroll
    for (int h = 0; h < 8; ++h) tot[h] = sc[255][h];
#pragma unroll
    for (int h = 0; h < 8; ++h) excl[h] = val[h] - c[h];
    // 8-aligned cumulative bases
    int bases[9];
    bases[0] = 0;
#pragma unroll
    for (int h = 0; h < 7; ++h) bases[h + 1] = (bases[h] + tot[h] + 7) & ~7;
    bases[8] = bases[7] + tot[7];
    // emit slots
#pragma unroll
    for (int h = 0; h < 8; ++h) {
      int pos = bases[h] + excl[h];
#pragma unroll
      for (int e = 0; e < 16; ++e) {
        if (myi[e] == h) { rows[pos] = t * 16 + e; ++pos; }
      }
    }
    // zero-fill alignment gaps and tail region up to 4160
    if (t < 56) {
      const int hh = t >> 3, j = t & 7;
      const int pos = bases[hh] + tot[hh] + j;
      if (pos < bases[hh + 1]) rows[pos] = 0;
    }
    if (t < 128) {
      const int pos = bases[8] + t;
      if (pos < 4160) rows[pos] = 0;
    }
    if (t < 8) cnt[t] = tot[t];
    if (t == 0) {
#pragma unroll
      for (int h = 0; h < 9; ++h) base8[h] = bases[h];
    }
    return;
  }

  // ---- transpose block: 64x64 tile of head h ----
  __shared__ unsigned short tile[64][68];
  const int h = bid >> 8;
  const int rem = bid & 255;
  const int d0 = (rem >> 4) << 6;
  const int f0 = (rem & 15) << 6;
  const int c4 = (t & 15) * 4;   // k-local 0..60
  const int r0 = t >> 4;
#pragma unroll
  for (int i = 0; i < 4; ++i) {
    const int r = r0 + i * 16;
    const float4 v = *(const float4*)(W + (size_t)(h * 1024 + d0 + r) * 1024 + f0 + c4);
    tile[r][c4 + 0] = f2bf(v.x);
    tile[r][c4 + 1] = f2bf(v.y);
    tile[r][c4 + 2] = f2bf(v.z);
    tile[r][c4 + 3] = f2bf(v.w);
  }
  __syncthreads();
  const int chunk = c4 >> 3;            // 16B chunk within 64-K group
  const int half = (c4 >> 2) & 1;       // 8B half within chunk
#pragma unroll
  for (int i = 0; i < 4; ++i) {
    const int fr = r0 + i * 16;
    const int frow = f0 + fr;
    ushort4 o;
    o.x = tile[c4 + 0][fr];
    o.y = tile[c4 + 1][fr];
    o.z = tile[c4 + 2][fr];
    o.w = tile[c4 + 3][fr];
    const int cS = chunk ^ (frow & 7);  // baked LDS swizzle
    *(ushort4*)((char*)Wt + (size_t)(h * 1024 + frow) * 2048 +
                (d0 << 1) + (cS << 4) + (half << 3)) = o;
  }
}

// Kernel 2: permuted gather-copy X row rows[slot] -> Ap[slot] (bf16,
// chunk-swizzled by slot&7 to match the LDS XOR on read).
__global__ __launch_bounds__(256) void k_gather(
    const float* __restrict__ X, const int* __restrict__ rows,
    unsigned short* __restrict__ Ap) {
  const int slot = blockIdx.x;
  const int b = rows[slot];
  const int t = threadIdx.x;
  const float4 v = *(const float4*)(X + (size_t)b * 1024 + t * 4);
  ushort4 o;
  o.x = f2bf(v.x); o.y = f2bf(v.y); o.z = f2bf(v.z); o.w = f2bf(v.w);
  const int g = t >> 4;                       // 64-K group
  const int cS = ((t >> 1) & 7) ^ (slot & 7); // baked LDS swizzle
  *(ushort4*)((char*)Ap + (size_t)slot * 2048 + (g << 7) + (cS << 4) +
              ((t & 1) << 3)) = o;
}

// Kernel 3: grouped GEMM, 128x128 tile, BK=64, 4 waves (2x2, each 64x64,
// 4x4 frag accs). Double-buffered 64KB LDS -> 2 blocks/CU (8 waves/CU).
// Staging sources LINEAR (swizzle pre-baked in Ap/Wt); counted vmcnt(8);
// two barriers per step (2nd guards buffer reuse). h=blk&7 -> XCD affinity.
__global__ __launch_bounds__(256) void k_gemm(
    const unsigned short* __restrict__ Ap, const unsigned short* __restrict__ Wt,
    const int* __restrict__ rows, const int* __restrict__ cnt,
    const int* __restrict__ base8,
    const float* __restrict__ bias, float* __restrict__ out) {
  __shared__ __align__(16) unsigned short As[2][128 * 64];
  __shared__ __align__(16) unsigned short Bs[2][128 * 64];

  const int blk = blockIdx.x;
  const int h = blk & 7;          // head -> XCD affinity
  const int nt = (blk >> 3) & 7;  // 8 n-tiles of 128
  const int mt = blk >> 6;        // up to 32 m-tiles of 128

  const int cnt_h = cnt[h];
  const int basep = base8[h];
  const int m0 = mt * 128;
  if (m0 >= cnt_h) return;
  const int n0 = nt * 128;

  const int t = threadIdx.x;
  const int lane = t & 63;
  const int wave = t >> 6;
  const int wr = wave >> 1, wc = wave & 1;

  // Linear per-row staging source pointers (clamped vs Ap's 4224 rows).
  const int srow = t >> 3;                 // 0..31
  const int scol = (t & 7) << 4;           // linear 16B chunk
  const char* aRow[4];
  const char* bRow[4];
#pragma unroll
  for (int r = 0; r < 4; ++r) {
    int ar = basep + m0 + r * 32 + srow;
    ar = ar < 4223 ? ar : 4223;
    aRow[r] = (const char*)Ap + (size_t)ar * 2048 + scol;
    bRow[r] = (const char*)Wt + (size_t)(h * 1024 + n0 + r * 32 + srow) * 2048 + scol;
  }

  f32x4 acc[4][4];
#pragma unroll
  for (int m = 0; m < 4; ++m)
#pragma unroll
    for (int n = 0; n < 4; ++n)
      acc[m][n] = (f32x4){0.f, 0.f, 0.f, 0.f};

  auto stage = [&](int s, int k0) {  // 8 gload16 per thread
#pragma unroll
    for (int r = 0; r < 4; ++r)
      gload16(aRow[r] + k0 * 2, (char*)(&As[s][0]) + r * 4096 + t * 16);
#pragma unroll
    for (int r = 0; r < 4; ++r)
      gload16(bRow[r] + k0 * 2, (char*)(&Bs[s][0]) + r * 4096 + t * 16);
  };

  const int swz = (lane & 7) << 4;
  const int ra = (wr * 64 + (lane & 15)) * 128;
  const int rb = (wc * 64 + (lane & 15)) * 128;
  const int kc = (lane >> 4) << 4;

  auto compute = [&](int s) {
    const char* ab = (const char*)(&As[s][0]);
    const char* bb = (const char*)(&Bs[s][0]);
#pragma unroll
    for (int ksub = 0; ksub < 2; ++ksub) {
      const int co = ((ksub * 64) + kc) ^ swz;
      bf16x8 af[4], bfr[4];
#pragma unroll
      for (int a = 0; a < 4; ++a)
        af[a] = *(const bf16x8*)(ab + ra + a * 2048 + co);
#pragma unroll
      for (int b = 0; b < 4; ++b)
        bfr[b] = *(const bf16x8*)(bb + rb + b * 2048 + co);
#pragma unroll
      for (int a = 0; a < 4; ++a)
#pragma unroll
        for (int b = 0; b < 4; ++b)
          acc[a][b] = __builtin_amdgcn_mfma_f32_16x16x32_bf16(af[a], bfr[b], acc[a][b], 0, 0, 0);
    }
  };

  stage(0, 0);
  stage(1, 64);

  for (int ts = 0; ts < 14; ++ts) {
    WAITV(8);                         // stage ts landed; ts+1 stays in flight
    __builtin_amdgcn_s_barrier();
    __builtin_amdgcn_sched_barrier(0);
    compute(ts & 1);
    __builtin_amdgcn_s_barrier();     // all waves done reading buf ts&1
    __builtin_amdgcn_sched_barrier(0);
    stage(ts & 1, (ts + 2) * 64);
    __builtin_amdgcn_sched_barrier(0);
  }
  WAITV(8);
  __builtin_amdgcn_s_barrier();
  __builtin_amdgcn_sched_barrier(0);
  compute(0);
  WAITV(0);
  __builtin_amdgcn_s_barrier();
  __builtin_amdgcn_sched_barrier(0);
  compute(1);

  // Epilogue: scatter through rows[] map, add bias (fp32).
  int rmap[4][4];
  bool vld[4][4];
#pragma unroll
  for (int m = 0; m < 4; ++m) {
#pragma unroll
    for (int j = 0; j < 4; ++j) {
      const int lr = wr * 64 + m * 16 + (lane >> 4) * 4 + j;
      const bool v = (m0 + lr) < cnt_h;
      vld[m][j] = v;
      rmap[m][j] = v ? rows[basep + m0 + lr] : 0;
    }
  }
#pragma unroll
  for (int n = 0; n < 4; ++n) {
    const int c = n0 + wc * 64 + n * 16 + (lane & 15);
    const float bv = bias[h * 1024 + c];
#pragma unroll
    for (int m = 0; m < 4; ++m) {
#pragma unroll
      for (int j = 0; j < 4; ++j) {
        if (vld[m][j])
          out[(size_t)rmap[m][j] * 1024 + c] = acc[m][n][j] + bv;
      }
    }
  }
}

extern "C" void kernel_launch(void* const* d_in, const int* in_sizes, int n_in,
                              void* d_out, int out_size, void* d_ws, size_t ws_size,
                              hipStream_t stream) {
  const float* X = (const float*)d_in[0];
  const int* idx = (const int*)d_in[1];
  const float* W = (const float*)d_in[2];
  const float* bias = (const float*)d_in[3];
  float* out = (float*)d_out;

  char* ws = (char*)d_ws;
  int* cnt = (int*)ws;                                   // 8 ints @ 0
  int* base8 = (int*)(ws + 64);                          // 9 ints @ 64
  int* rows = (int*)(ws + 256);                          // 4160 ints
  unsigned short* Wt = (unsigned short*)(ws + 32768);    // 8*1024 rows * 2KB = 16 MB
  unsigned short* Ap = (unsigned short*)(ws + 32768 + 16777216);  // 4224 rows * 2KB

  k_prep<<<dim3(2049), 256, 0, stream>>>(W, idx, Wt, cnt, base8, rows);
  k_gather<<<dim3(4160), 256, 0, stream>>>(X, rows, Ap);
  k_gemm<<<dim3(8 * 8 * 32), 256, 0, stream>>>(Ap, Wt, rows, cnt, base8, bias, out);
}

// Round 6
// 47.310 us; speedup vs baseline: 1.3311x; 1.1661x over previous
//
#include <hip/hip_runtime.h>

// MultiHeadDense: out[b] = x[b] @ W[idx[b]] + bias[idx[b]]
// B=4096, D=1024, F=1024, H=8. fp32 in/out; bf16 MFMA internally.
// Round 6: TLP is the binding constraint (per-step stall ~ 1/waves_per_CU).
// k_gemm tile 128Mx64N -> 512 working blocks = 2 blocks/CU, 8 waves/CU
// (vs 4). BK=64 dbuf (48KB LDS, capacity 3/CU), counted vmcnt(6), baked
// LDS swizzle (linear staging sources), h=blk&7 XCD affinity.

typedef __attribute__((ext_vector_type(8))) short bf16x8;
typedef __attribute__((ext_vector_type(4))) float f32x4;

#define WAITV(N) asm volatile("s_waitcnt vmcnt(" #N ")" ::: "memory")

static __device__ __forceinline__ unsigned short f2bf(float f) {
  union { float f; unsigned int u; } c; c.f = f;
  unsigned int u = c.u;
  return (unsigned short)((u + 0x7fffu + ((u >> 16) & 1u)) >> 16);
}

static __device__ __forceinline__ void gload16(const void* g, void* s) {
  __builtin_amdgcn_global_load_lds(
      (const __attribute__((address_space(1))) void*)g,
      (__attribute__((address_space(3))) void*)s, 16, 0, 0);
}

// Kernel 1 (fused): blocks 0..2047 transpose+convert W [H][D][F] fp32 ->
// Wt [H][F][D-swizzled] bf16 (chunk c of each 64-K group stored at c^(frow&7)).
// Block 2048: counting-sort scan of idx -> rows[] + cnt[] + base8[] (8-aligned
// head bases; gap slots zero-filled). No atomics anywhere.
__global__ __launch_bounds__(256) void k_prep(
    const float* __restrict__ W, const int* __restrict__ idx,
    unsigned short* __restrict__ Wt, int* __restrict__ cnt,
    int* __restrict__ base8, int* __restrict__ rows) {
  const int bid = blockIdx.x;
  const int t = threadIdx.x;

  if (bid >= 2048) {
    __shared__ int sc[256][8];
    int myi[16];
#pragma unroll
    for (int i = 0; i < 4; ++i) {
      const int4 v = *(const int4*)(idx + t * 16 + i * 4);
      myi[i * 4 + 0] = v.x; myi[i * 4 + 1] = v.y;
      myi[i * 4 + 2] = v.z; myi[i * 4 + 3] = v.w;
    }
    int c[8];
#pragma unroll
    for (int h = 0; h < 8; ++h) c[h] = 0;
#pragma unroll
    for (int e = 0; e < 16; ++e)
#pragma unroll
      for (int h = 0; h < 8; ++h) c[h] += (myi[e] == h) ? 1 : 0;

    int val[8];
#pragma unroll
    for (int h = 0; h < 8; ++h) { val[h] = c[h]; sc[t][h] = c[h]; }
    __syncthreads();
    for (int off = 1; off < 256; off <<= 1) {
      int nb[8];
#pragma unroll
      for (int h = 0; h < 8; ++h) nb[h] = (t >= off) ? sc[t - off][h] : 0;
      __syncthreads();
#pragma unroll
      for (int h = 0; h < 8; ++h) { val[h] += nb[h]; sc[t][h] = val[h]; }
      __syncthreads();
    }
    int tot[8], excl[8];
#pragma unroll
    for (int h = 0; h < 8; ++h) tot[h] = sc[255][h];
#pragma unroll
    for (int h = 0; h < 8; ++h) excl[h] = val[h] - c[h];
    int bases[9];
    bases[0] = 0;
#pragma unroll
    for (int h = 0; h < 7; ++h) bases[h + 1] = (bases[h] + tot[h] + 7) & ~7;
    bases[8] = bases[7] + tot[7];
#pragma unroll
    for (int h = 0; h < 8; ++h) {
      int pos = bases[h] + excl[h];
#pragma unroll
      for (int e = 0; e < 16; ++e) {
        if (myi[e] == h) { rows[pos] = t * 16 + e; ++pos; }
      }
    }
    if (t < 56) {
      const int hh = t >> 3, j = t & 7;
      const int pos = bases[hh] + tot[hh] + j;
      if (pos < bases[hh + 1]) rows[pos] = 0;
    }
    if (t < 128) {
      const int pos = bases[8] + t;
      if (pos < 4160) rows[pos] = 0;
    }
    if (t < 8) cnt[t] = tot[t];
    if (t == 0) {
#pragma unroll
      for (int h = 0; h < 9; ++h) base8[h] = bases[h];
    }
    return;
  }

  // ---- transpose block: 64x64 tile of head h ----
  __shared__ unsigned short tile[64][68];
  const int h = bid >> 8;
  const int rem = bid & 255;
  const int d0 = (rem >> 4) << 6;
  const int f0 = (rem & 15) << 6;
  const int c4 = (t & 15) * 4;
  const int r0 = t >> 4;
#pragma unroll
  for (int i = 0; i < 4; ++i) {
    const int r = r0 + i * 16;
    const float4 v = *(const float4*)(W + (size_t)(h * 1024 + d0 + r) * 1024 + f0 + c4);
    tile[r][c4 + 0] = f2bf(v.x);
    tile[r][c4 + 1] = f2bf(v.y);
    tile[r][c4 + 2] = f2bf(v.z);
    tile[r][c4 + 3] = f2bf(v.w);
  }
  __syncthreads();
  const int chunk = c4 >> 3;
  const int half = (c4 >> 2) & 1;
#pragma unroll
  for (int i = 0; i < 4; ++i) {
    const int fr = r0 + i * 16;
    const int frow = f0 + fr;
    ushort4 o;
    o.x = tile[c4 + 0][fr];
    o.y = tile[c4 + 1][fr];
    o.z = tile[c4 + 2][fr];
    o.w = tile[c4 + 3][fr];
    const int cS = chunk ^ (frow & 7);  // baked LDS swizzle
    *(ushort4*)((char*)Wt + (size_t)(h * 1024 + frow) * 2048 +
                (d0 << 1) + (cS << 4) + (half << 3)) = o;
  }
}

// Kernel 2: permuted gather-copy X row rows[slot] -> Ap[slot] (bf16,
// chunk-swizzled by slot&7 to match the LDS XOR on read).
__global__ __launch_bounds__(256) void k_gather(
    const float* __restrict__ X, const int* __restrict__ rows,
    unsigned short* __restrict__ Ap) {
  const int slot = blockIdx.x;
  const int b = rows[slot];
  const int t = threadIdx.x;
  const float4 v = *(const float4*)(X + (size_t)b * 1024 + t * 4);
  ushort4 o;
  o.x = f2bf(v.x); o.y = f2bf(v.y); o.z = f2bf(v.z); o.w = f2bf(v.w);
  const int g = t >> 4;
  const int cS = ((t >> 1) & 7) ^ (slot & 7);
  *(ushort4*)((char*)Ap + (size_t)slot * 2048 + (g << 7) + (cS << 4) +
              ((t & 1) << 3)) = o;
}

// Kernel 3: grouped GEMM, 128Mx64N tile, BK=64, 4 waves (2x2, each 64x32,
// 4x2 frag accs). dbuf 48KB LDS -> 3 blocks/CU capacity; 512 working blocks
// -> 2 blocks/CU resident, 8 waves/CU. Linear staging (swizzle baked in
// Ap/Wt), counted vmcnt(6) (never 0 mid-loop). h=blk&7 -> XCD affinity.
__global__ __launch_bounds__(256) void k_gemm(
    const unsigned short* __restrict__ Ap, const unsigned short* __restrict__ Wt,
    const int* __restrict__ rows, const int* __restrict__ cnt,
    const int* __restrict__ base8,
    const float* __restrict__ bias, float* __restrict__ out) {
  __shared__ __align__(16) unsigned short As[2][128 * 64];
  __shared__ __align__(16) unsigned short Bs[2][64 * 64];

  const int blk = blockIdx.x;
  const int h = blk & 7;           // head -> XCD affinity
  const int nt = (blk >> 3) & 15;  // 16 n-tiles of 64
  const int mt = blk >> 7;         // up to 16 m-tiles of 128

  const int cnt_h = cnt[h];
  const int basep = base8[h];
  const int m0 = mt * 128;
  if (m0 >= cnt_h) return;
  const int n0 = nt * 64;

  const int t = threadIdx.x;
  const int lane = t & 63;
  const int wave = t >> 6;
  const int wr = wave >> 1, wc = wave & 1;  // wave tile: 64 rows x 32 cols

  // Linear per-row staging source pointers (A clamped vs Ap's 4224 rows).
  const int srow = t >> 3;                 // 0..31
  const int scol = (t & 7) << 4;           // linear 16B chunk
  const char* aRow[4];
  const char* bRow[2];
#pragma unroll
  for (int r = 0; r < 4; ++r) {
    int ar = basep + m0 + r * 32 + srow;
    ar = ar < 4223 ? ar : 4223;
    aRow[r] = (const char*)Ap + (size_t)ar * 2048 + scol;
  }
#pragma unroll
  for (int r = 0; r < 2; ++r)
    bRow[r] = (const char*)Wt + (size_t)(h * 1024 + n0 + r * 32 + srow) * 2048 + scol;

  f32x4 acc[4][2];
#pragma unroll
  for (int m = 0; m < 4; ++m)
#pragma unroll
    for (int n = 0; n < 2; ++n)
      acc[m][n] = (f32x4){0.f, 0.f, 0.f, 0.f};

  auto stage = [&](int s, int k0) {  // 6 gload16 per thread (4 A + 2 B)
#pragma unroll
    for (int r = 0; r < 4; ++r)
      gload16(aRow[r] + k0 * 2, (char*)(&As[s][0]) + r * 4096 + t * 16);
#pragma unroll
    for (int r = 0; r < 2; ++r)
      gload16(bRow[r] + k0 * 2, (char*)(&Bs[s][0]) + r * 4096 + t * 16);
  };

  const int swz = (lane & 7) << 4;
  const int ra = (wr * 64 + (lane & 15)) * 128;  // A frag byte base
  const int rb = (wc * 32 + (lane & 15)) * 128;  // B frag byte base
  const int kc = (lane >> 4) << 4;

  auto compute = [&](int s) {
    const char* ab = (const char*)(&As[s][0]);
    const char* bb = (const char*)(&Bs[s][0]);
#pragma unroll
    for (int ksub = 0; ksub < 2; ++ksub) {
      const int co = ((ksub * 64) + kc) ^ swz;
      bf16x8 af[4], bfr[2];
#pragma unroll
      for (int a = 0; a < 4; ++a)
        af[a] = *(const bf16x8*)(ab + ra + a * 2048 + co);
#pragma unroll
      for (int b = 0; b < 2; ++b)
        bfr[b] = *(const bf16x8*)(bb + rb + b * 2048 + co);
#pragma unroll
      for (int a = 0; a < 4; ++a)
#pragma unroll
        for (int b = 0; b < 2; ++b)
          acc[a][b] = __builtin_amdgcn_mfma_f32_16x16x32_bf16(af[a], bfr[b], acc[a][b], 0, 0, 0);
    }
  };

  stage(0, 0);
  stage(1, 64);

  for (int ts = 0; ts < 14; ++ts) {
    WAITV(6);                         // stage ts landed; ts+1 stays in flight
    __builtin_amdgcn_s_barrier();
    __builtin_amdgcn_sched_barrier(0);
    compute(ts & 1);
    __builtin_amdgcn_s_barrier();     // all waves done reading buf ts&1
    __builtin_amdgcn_sched_barrier(0);
    stage(ts & 1, (ts + 2) * 64);
    __builtin_amdgcn_sched_barrier(0);
  }
  WAITV(6);
  __builtin_amdgcn_s_barrier();
  __builtin_amdgcn_sched_barrier(0);
  compute(0);
  WAITV(0);
  __builtin_amdgcn_s_barrier();
  __builtin_amdgcn_sched_barrier(0);
  compute(1);

  // Epilogue: scatter through rows[] map, add bias (fp32).
  int rmap[4][4];
  bool vld[4][4];
#pragma unroll
  for (int m = 0; m < 4; ++m) {
#pragma unroll
    for (int j = 0; j < 4; ++j) {
      const int lr = wr * 64 + m * 16 + (lane >> 4) * 4 + j;
      const bool v = (m0 + lr) < cnt_h;
      vld[m][j] = v;
      rmap[m][j] = v ? rows[basep + m0 + lr] : 0;
    }
  }
#pragma unroll
  for (int n = 0; n < 2; ++n) {
    const int c = n0 + wc * 32 + n * 16 + (lane & 15);
    const float bv = bias[h * 1024 + c];
#pragma unroll
    for (int m = 0; m < 4; ++m) {
#pragma unroll
      for (int j = 0; j < 4; ++j) {
        if (vld[m][j])
          out[(size_t)rmap[m][j] * 1024 + c] = acc[m][n][j] + bv;
      }
    }
  }
}

extern "C" void kernel_launch(void* const* d_in, const int* in_sizes, int n_in,
                              void* d_out, int out_size, void* d_ws, size_t ws_size,
                              hipStream_t stream) {
  const float* X = (const float*)d_in[0];
  const int* idx = (const int*)d_in[1];
  const float* W = (const float*)d_in[2];
  const float* bias = (const float*)d_in[3];
  float* out = (float*)d_out;

  char* ws = (char*)d_ws;
  int* cnt = (int*)ws;                                   // 8 ints @ 0
  int* base8 = (int*)(ws + 64);                          // 9 ints @ 64
  int* rows = (int*)(ws + 256);                          // 4160 ints
  unsigned short* Wt = (unsigned short*)(ws + 32768);    // 8*1024 rows * 2KB = 16 MB
  unsigned short* Ap = (unsigned short*)(ws + 32768 + 16777216);  // 4224 rows * 2KB

  k_prep<<<dim3(2049), 256, 0, stream>>>(W, idx, Wt, cnt, base8, rows);
  k_gather<<<dim3(4160), 256, 0, stream>>>(X, rows, Ap);
  // 8 heads (xcd-affine) x 16 n-tiles x 16 m-tiles (early-return past cnt_h)
  k_gemm<<<dim3(8 * 16 * 16), 256, 0, stream>>>(Ap, Wt, rows, cnt, base8, bias, out);
}